// Round 1
// baseline (324.035 us; speedup 1.0000x reference)
//
#include <hip/hip_runtime.h>

#define PAD_IDX 1

// Tile: 64 q x 128 d per 256-thread block. E = 64 (embed dim, fixed).
// LDS layout is k-major with padded strides to avoid bank conflicts:
//   As[k*68 + r]  (64x64 q-tile, stride 68 floats)
//   Bs[k*132 + r] (64x128 d-tile, stride 132 floats)
__global__ __launch_bounds__(256) void lm_main(
    const float* __restrict__ embed,
    const int* __restrict__ quer,
    const int* __restrict__ doc,
    const int* __restrict__ para,
    float* __restrict__ out,
    int Lq, int D)
{
    const int E  = 64;
    const int QT = 64, DT = 128;
    const int QS = 68, DS = 132;   // padded LDS row strides (floats)

    __shared__ float As[64 * 68];
    __shared__ float Bs[64 * 132];
    __shared__ int   qid_s[QT];
    __shared__ int   did_s[DT];

    const int tid    = threadIdx.x;
    const int bd     = blockIdx.x;
    const int bq     = blockIdx.y;
    const int d_base = bd * DT;
    const int q_base = bq * QT;

    // ---- stage Q tile: 4 threads per row, each loads 16 floats ----
    {
        const int r    = tid >> 2;        // 0..63
        const int part = tid & 3;         // 0..3
        const int qg   = q_base + r;
        const int qid  = (qg < Lq) ? quer[qg] : PAD_IDX;
        const float* rowp = embed + (size_t)qid * E + part * 16;
        float v[16];
        #pragma unroll
        for (int c = 0; c < 4; ++c) {
            float4 f = ((const float4*)rowp)[c];
            v[c*4+0] = f.x; v[c*4+1] = f.y; v[c*4+2] = f.z; v[c*4+3] = f.w;
        }
        float s = 0.f;
        #pragma unroll
        for (int c = 0; c < 16; ++c) s += v[c] * v[c];
        // reduce across the 4 lanes sharing this row (lanes r*4 .. r*4+3)
        s += __shfl_xor(s, 1);
        s += __shfl_xor(s, 2);
        const float inv = (qid != PAD_IDX && qg < Lq && s > 0.f) ? rsqrtf(s) : 0.f;
        #pragma unroll
        for (int c = 0; c < 16; ++c)
            As[(part * 16 + c) * QS + r] = v[c] * inv;
        if (part == 0) qid_s[r] = qid;
    }

    // ---- stage D tile: 2 threads per row, each loads 32 floats ----
    {
        const int r    = tid >> 1;        // 0..127
        const int half = tid & 1;
        const int dg   = d_base + r;
        const int did  = (dg < D) ? doc[dg] : PAD_IDX;
        const float* rowp = embed + (size_t)did * E + half * 32;
        float v[32];
        #pragma unroll
        for (int c = 0; c < 8; ++c) {
            float4 f = ((const float4*)rowp)[c];
            v[c*4+0] = f.x; v[c*4+1] = f.y; v[c*4+2] = f.z; v[c*4+3] = f.w;
        }
        float s = 0.f;
        #pragma unroll
        for (int c = 0; c < 32; ++c) s += v[c] * v[c];
        s += __shfl_xor(s, 1);            // combine the two halves
        const float inv = (dg < D && did != PAD_IDX && s > 0.f) ? rsqrtf(s) : 0.f;
        #pragma unroll
        for (int c = 0; c < 32; ++c)
            Bs[(half * 32 + c) * DS + r] = v[c] * inv;
        if (half == 0) did_s[r] = did;
    }

    __syncthreads();

    // ---- compute: 4 q x 8 d micro-tile per thread ----
    const int tq = tid >> 4;   // 0..15 -> q quad
    const int td = tid & 15;   // 0..15 -> d oct
    float acc[4][8];
    #pragma unroll
    for (int i = 0; i < 4; ++i)
        #pragma unroll
        for (int j = 0; j < 8; ++j) acc[i][j] = 0.f;

    #pragma unroll 8
    for (int k = 0; k < E; ++k) {
        const float4 a  = *(const float4*)&As[k * QS + tq * 4];
        const float4 b0 = *(const float4*)&Bs[k * DS + td * 8];
        const float4 b1 = *(const float4*)&Bs[k * DS + td * 8 + 4];
        const float av[4] = {a.x, a.y, a.z, a.w};
        const float bv[8] = {b0.x, b0.y, b0.z, b0.w, b1.x, b1.y, b1.z, b1.w};
        #pragma unroll
        for (int i = 0; i < 4; ++i)
            #pragma unroll
            for (int j = 0; j < 8; ++j)
                acc[i][j] = fmaf(av[i], bv[j], acc[i][j]);
    }

    // ---- store: out[0] = xor (0/1), out[1] = cos, both at
    //      idx = (d/ps)*(Lq*ps) + q*ps + (d%ps) ----
    const int ps        = para[0];
    const int rowstride = Lq * ps;             // elements per para-block
    const size_t cos_off = (size_t)Lq * (size_t)D;

    #pragma unroll
    for (int i = 0; i < 4; ++i) {
        const int q  = q_base + tq * 4 + i;
        if (q >= Lq) continue;
        const int qi = qid_s[tq * 4 + i];
        const int d0 = d_base + td * 8;
        int p = d0 / ps;
        int s = d0 - p * ps;
        #pragma unroll
        for (int j = 0; j < 8; ++j) {
            const int d = d0 + j;
            if (d < D) {
                const size_t idx = (size_t)p * rowstride + (size_t)q * ps + s;
                out[idx]           = (qi == did_s[td * 8 + j]) ? 1.0f : 0.0f;
                out[cos_off + idx] = acc[i][j];
            }
            if (++s == ps) { s = 0; ++p; }
        }
    }
}

extern "C" void kernel_launch(void* const* d_in, const int* in_sizes, int n_in,
                              void* d_out, int out_size, void* d_ws, size_t ws_size,
                              hipStream_t stream) {
    const float* embed = (const float*)d_in[0];
    const int*   quer  = (const int*)d_in[1];
    const int*   doc   = (const int*)d_in[2];
    const int*   para  = (const int*)d_in[3];
    float*       out   = (float*)d_out;

    const int Lq = in_sizes[1];      // 512
    const int D  = in_sizes[2];      // 100000

    const int qBlocks = (Lq + 63) / 64;
    const int dBlocks = (D + 127) / 128;
    dim3 grid(dBlocks, qBlocks);
    lm_main<<<grid, 256, 0, stream>>>(embed, quer, doc, para, out, Lq, D);
}